// Round 8
// baseline (29740.933 us; speedup 1.0000x reference)
//
#include <hip/hip_runtime.h>
#include <math.h>

#define T_STEPS 512
#define BATCH   128
#define HDIM    300
#define M       20
#define M2      10   // j's owned per block

// ---------------- JAX threefry2x32 noise replication ----------------
__device__ __forceinline__ unsigned rotl32(unsigned v, int r) {
    return (v << r) | (v >> (32 - r));
}

__device__ float jax_noise(unsigned i) {
#pragma clang fp contract(off)
    unsigned x0 = 0u;
    unsigned x1 = i;
    const unsigned ks0 = 0u, ks1 = 42u, ks2 = 0u ^ 42u ^ 0x1BD11BDAu;
    x0 += ks0; x1 += ks1;
    x0 += x1; x1 = rotl32(x1, 13); x1 ^= x0;
    x0 += x1; x1 = rotl32(x1, 15); x1 ^= x0;
    x0 += x1; x1 = rotl32(x1, 26); x1 ^= x0;
    x0 += x1; x1 = rotl32(x1, 6);  x1 ^= x0;
    x0 += ks1; x1 += ks2 + 1u;
    x0 += x1; x1 = rotl32(x1, 17); x1 ^= x0;
    x0 += x1; x1 = rotl32(x1, 29); x1 ^= x0;
    x0 += x1; x1 = rotl32(x1, 16); x1 ^= x0;
    x0 += x1; x1 = rotl32(x1, 24); x1 ^= x0;
    x0 += ks2; x1 += ks0 + 2u;
    x0 += x1; x1 = rotl32(x1, 13); x1 ^= x0;
    x0 += x1; x1 = rotl32(x1, 15); x1 ^= x0;
    x0 += x1; x1 = rotl32(x1, 26); x1 ^= x0;
    x0 += x1; x1 = rotl32(x1, 6);  x1 ^= x0;
    x0 += ks0; x1 += ks1 + 3u;
    x0 += x1; x1 = rotl32(x1, 17); x1 ^= x0;
    x0 += x1; x1 = rotl32(x1, 29); x1 ^= x0;
    x0 += x1; x1 = rotl32(x1, 16); x1 ^= x0;
    x0 += x1; x1 = rotl32(x1, 24); x1 ^= x0;
    x0 += ks1; x1 += ks2 + 4u;
    x0 += x1; x1 = rotl32(x1, 13); x1 ^= x0;
    x0 += x1; x1 = rotl32(x1, 15); x1 ^= x0;
    x0 += x1; x1 = rotl32(x1, 26); x1 ^= x0;
    x0 += x1; x1 = rotl32(x1, 6);  x1 ^= x0;
    x0 += ks2; x1 += ks0 + 5u;

    const unsigned bits = x0 ^ x1;
    const unsigned fb = (bits >> 9) | 0x3f800000u;
    float f = __uint_as_float(fb) - 1.0f;
    const float span = 1.0f - 0.01f;
    float v = f * span;
    v = v + 0.01f;
    return fmaxf(0.01f, v);
}

#define FOR5(X) X(0) X(1) X(2) X(3) X(4)

// ---------------- paired persistent kernel, fused A+B loop ----------------
// grid = 256 blocks: bid -> batch b = bid&127, j-half = bid>>7 (rows jb2..jb2+9).
// Partner bid^128 (same XCD under %8 round-robin). Exchange 10 sim floats/step.
//
// R8: back to R6's all-wave Phase-B mapping (R7 role-split regressed: B on 5
// waves doubled its latency-bound critical path). Phase A is FUSED into the
// same k-loop as independent ILP that fills B's ds_read stall slots:
//   threads 0-299  (g0): B col c, local rows 0-4  +  a1/ae GEMVs
//   threads 300-599(g1): B col c, local rows 5-9  +  au GEMV
// Everything prefetched one iteration ahead (weights, mem rows, h) in named
// rotation registers (R5-proven; arrays would go to scratch - R1/R2 lesson).
// h read from global (L1-resident row) -> 4 barriers/step.
__global__ void __launch_bounds__(640, 3)
wm_kernel(const float* __restrict__ hs,   // (T,B,H)
          const float* __restrict__ msk,  // (T,B)
          const float* __restrict__ We1,  // (300,300)
          const float* __restrict__ be1,  // (300)
          const float* __restrict__ We2,  // (300,1)
          const float* __restrict__ be2,  // (1)
          const float* __restrict__ Ws1,  // (901,300)
          const float* __restrict__ bs1,  // (300)
          const float* __restrict__ Ws2,  // (300,1)
          const float* __restrict__ bs2,  // (1)
          const float* __restrict__ Wu,   // (600,300)
          const float* __restrict__ bu,   // (300)
          float* __restrict__ out,
          float* __restrict__ ws)         // d_ws: vals[256][16] @0, flags @+16KB
{
    __shared__ __align__(16) float sh_mem[M2][HDIM];
    __shared__ __align__(16) float sh_sim[M2][HDIM];
    __shared__ __align__(16) float sh_cand[M2][HDIM];
    __shared__ __align__(16) float sh_usage[12288];  // [M] used; oversized -> 1 block/CU
    __shared__ float sh_simpart[5][M2];
    __shared__ float sh_entpart[5];
    __shared__ float sh_ow[M];
    __shared__ float sh_indv[M];

    const int bid   = blockIdx.x;
    const int b     = bid & 127;
    const int jhalf = bid >> 7;
    const int jb2   = jhalf * 10;         // own global j-base
    const int pbase = 10 - jb2;           // partner global j-base
    const int pbid  = bid ^ 128;

    float*    vals_me = ws + (size_t)bid * 16;
    float*    vals_p  = ws + (size_t)pbid * 16;
    unsigned* flag_me = (unsigned*)(ws + 4096) + (size_t)bid * 16;
    unsigned* flag_p  = (unsigned*)(ws + 4096) + (size_t)pbid * 16;

    const int tid  = threadIdx.x;
    const int wave = tid >> 6;   // 0..9
    const int lane = tid & 63;

    const bool act = tid < 600;
    const int  g   = (tid < 300) ? 0 : 1;     // role group
    const int  c   = (tid < 300) ? tid : (tid - 300);   // column 0..299
    const int  jl  = g * 5;                   // local row base (0 or 5)

    // ---- init state ----
    for (int idx = tid; idx < M2 * HDIM; idx += 640) ((float*)sh_mem)[idx] = 0.0f;
    if (tid < M) sh_usage[tid] = 0.0f;

    const float be2v = be2[0];
    const float bs2v = bs2[0];
    // step-invariant per-column scalars
    float bs1c = 0.f, be1c = 0.f, we2c = 0.f, ws2c = 0.f, w900c = 0.f, buc = 0.f;
    if (act) {
        if (g == 0) {
            bs1c = bs1[c]; be1c = be1[c]; we2c = We2[c];
            ws2c = Ws2[c]; w900c = Ws1[900 * 300 + c];
        } else {
            buc = bu[c];
        }
    }
    __syncthreads();

    for (int t = 0; t < T_STEPS; ++t) {
        const int tb = t * BATCH + b;
        const float* __restrict__ hrow = hs + (size_t)tb * HDIM;   // L1-resident

        float hb1reg = 0.f, hwureg = 0.f;
        float a1 = 0.f, ae = 0.f, au = 0.f;

        // ---- fused Phase A+B k-loop ----
#define DECL_ACC(jj) float aS_##jj = 0.f, aC_##jj = 0.f;
        FOR5(DECL_ACC)
#undef DECL_ACC
        if (act) {
            const float* qa  = Ws1 + c;            // rows 0..299   (mem)
            const float* qc  = Ws1 + 180000 + c;   // rows 600..899 (h*mem)
            const float* qu  = Wu + 90000 + c;     // rows 300..599 (mem)
            const float* pA1 = Ws1 + 90000 + c;    // g0: a1 (rows 300..599)
            const float* pAe = We1 + c;            // g0: ae
            const float* pAu = Wu + c;             // g1: au (rows 0..299)

            // preload k=0
            float A0 = qa[0], A1v = qa[300], A2 = qa[600], A3 = qa[900];
            float C0 = qc[0], C1 = qc[300], C2 = qc[600], C3 = qc[900];
            float U0 = qu[0], U1 = qu[300], U2 = qu[600], U3 = qu[900];
            float4 H = *(const float4*)&hrow[0];
#define PRELOAD_M(jj) float4 M_##jj = *(const float4*)&sh_mem[jl + jj][0];
            FOR5(PRELOAD_M)
#undef PRELOAD_M

            for (int k = 0; k < HDIM; k += 4) {
                const int kn = (k + 4 < HDIM) ? (k + 4) : 0;   // clamped prefetch
                // ---- prefetch next iteration ----
                const float* na = qa + kn * 300;
                const float* nc = qc + kn * 300;
                const float* nu = qu + kn * 300;
                float NA0 = na[0], NA1 = na[300], NA2 = na[600], NA3 = na[900];
                float NC0 = nc[0], NC1 = nc[300], NC2 = nc[600], NC3 = nc[900];
                float NU0 = nu[0], NU1 = nu[300], NU2 = nu[600], NU3 = nu[900];
                float4 NH = *(const float4*)&hrow[kn];
#define PF_M(jj) float4 NM_##jj = *(const float4*)&sh_mem[jl + jj][kn];
                FOR5(PF_M)
#undef PF_M

                // ---- Phase B compute ----
                float w0 = fmaf(H.x, C0, A0);
                float w1 = fmaf(H.y, C1, A1v);
                float w2 = fmaf(H.z, C2, A2);
                float w3 = fmaf(H.w, C3, A3);
#define ACC_J(jj) { \
                aS_##jj += M_##jj.x * w0 + M_##jj.y * w1 + M_##jj.z * w2 + M_##jj.w * w3; \
                aC_##jj += M_##jj.x * U0 + M_##jj.y * U1 + M_##jj.z * U2 + M_##jj.w * U3; }
                FOR5(ACC_J)
#undef ACC_J

                // ---- Phase A compute (independent ILP filling B's stalls) ----
                if (g == 0) {
                    const float* q1 = pA1 + k * 300;
                    const float* qe = pAe + k * 300;
                    a1 += H.x * q1[0] + H.y * q1[300] + H.z * q1[600] + H.w * q1[900];
                    ae += H.x * qe[0] + H.y * qe[300] + H.z * qe[600] + H.w * qe[900];
                } else {
                    const float* q2 = pAu + k * 300;
                    au += H.x * q2[0] + H.y * q2[300] + H.z * q2[600] + H.w * q2[900];
                }

                // ---- rotate ----
                A0 = NA0; A1v = NA1; A2 = NA2; A3 = NA3;
                C0 = NC0; C1 = NC1; C2 = NC2; C3 = NC3;
                U0 = NU0; U1 = NU1; U2 = NU2; U3 = NU3;
                H = NH;
#define ROT_M(jj) M_##jj = NM_##jj;
                FOR5(ROT_M)
#undef ROT_M
            }
#define WB(jj) { sh_sim[jl + jj][c] = aS_##jj; sh_cand[jl + jj][c] = aC_##jj; }
            FOR5(WB)
#undef WB
            hb1reg = a1 + bs1c;
            hwureg = au + buc;
        }
        __syncthreads();   // (1) sim/cand partials ready

        // ---- sim finish + ent partials (waves 0-4; g0 threads hold hb1reg) ----
        if (wave < 5) {
            float er = (tid < 300) ? (fmaxf(ae + be1c, 0.0f) * we2c) : 0.0f;
            for (int off = 32; off; off >>= 1) er += __shfl_xor(er, off, 64);
            if (lane == 0) sh_entpart[wave] = er;
#pragma unroll
            for (int jj = 0; jj < M2; ++jj) {
                float v = 0.f;
                if (tid < 300) {
                    float pre = sh_sim[jj][c] + hb1reg + sh_usage[jb2 + jj] * w900c;
                    v = fmaxf(pre, 0.0f) * ws2c;
                }
                for (int off = 32; off; off >>= 1) v += __shfl_xor(v, off, 64);
                if (lane == 0) sh_simpart[wave][jj] = v;
            }
        }
        __syncthreads();   // (2)

        // ---- Phase C: exchange + decision (wave 0; redundant on both halves) ----
        if (wave == 0) {
            float sown = 0.f;
            if (lane < M2) {
                sown = sh_simpart[0][lane] + sh_simpart[1][lane] + sh_simpart[2][lane]
                     + sh_simpart[3][lane] + sh_simpart[4][lane];
                __hip_atomic_store(&vals_me[lane], sown, __ATOMIC_RELAXED,
                                   __HIP_MEMORY_SCOPE_AGENT);
            }
            if (lane == 0) {
                __hip_atomic_store(flag_me, (unsigned)(t + 1), __ATOMIC_RELEASE,
                                   __HIP_MEMORY_SCOPE_AGENT);
                while (__hip_atomic_load(flag_p, __ATOMIC_ACQUIRE,
                                         __HIP_MEMORY_SCOPE_AGENT) < (unsigned)(t + 1))
                    __builtin_amdgcn_s_sleep(1);
            }
            float pvv = 0.f;
            if (lane >= pbase && lane < pbase + M2)
                pvv = __hip_atomic_load(&vals_p[lane - pbase], __ATOMIC_ACQUIRE,
                                        __HIP_MEMORY_SCOPE_AGENT);
            const float myv = __shfl(sown, lane - jb2, 64);

            const bool actc = lane < M;
            const bool own  = actc && (lane >= jb2) && (lane < jb2 + M2);
            float simj = -INFINITY, usg = 0.0f;
            if (actc) {
                simj = (own ? myv : pvv) + bs2v;
                usg  = sh_usage[lane];
            }
            float es = sh_entpart[0] + sh_entpart[1] + sh_entpart[2]
                     + sh_entpart[3] + sh_entpart[4] + be2v;
            const float entp = (1.0f / (1.0f + expf(-es))) * msk[tb];

            const float coref = (actc && usg > 0.0f) ? 1.0f : 0.0f;
            float comb = actc ? ((usg > 0.0f) ? simj : -10000.0f) : -INFINITY;
            float mx = comb;
            for (int off = 32; off; off >>= 1) mx = fmaxf(mx, __shfl_xor(mx, off, 64));
            mx = fmaxf(mx, 0.0f);
            float e = actc ? expf(comb - mx) : 0.0f;
            const float eM = expf(0.0f - mx);
            float den = e;
            for (int off = 32; off; off >>= 1) den += __shfl_xor(den, off, 64);
            den += eM;
            const float prob  = e / den;
            const float probM = eM / den;
            float masked = prob * coref;
            float msum = masked;
            for (int off = 32; off; off >>= 1) msum += __shfl_xor(msum, off, 64);
            msum += probM;
            const float dn = msum + 1e-8f;
            const float normj = masked / dn;
            const float normM = probM / dn;
            const float indv = actc ? (entp * normj) : 0.0f;
            const float ow_base = entp * normM;

            // nsim = softmax(sim)
            float nmx = simj;
            for (int off = 32; off; off >>= 1) nmx = fmaxf(nmx, __shfl_xor(nmx, off, 64));
            float ne = actc ? expf(simj - nmx) : 0.0f;
            float ns = ne;
            for (int off = 32; off; off >>= 1) ns += __shfl_xor(ns, off, 64);
            const float nsim = ne / ns;

            float ows = actc ? (((usg == 0.0f) ? nsim * 100000.0f : 0.0f) + (1.0f - usg))
                             : -INFINITY;
            float mv = ows;
            for (int off = 32; off; off >>= 1) mv = fmaxf(mv, __shfl_xor(mv, off, 64));

            float key = 0.0f;
            if (actc && ows == mv) key = jax_noise((unsigned)(tb * M + lane));
            float bv = actc ? key : -1.0f;
            int bi = actc ? lane : 1023;
            for (int off = 32; off; off >>= 1) {
                float ov = __shfl_xor(bv, off, 64);
                int oi = __shfl_xor(bi, off, 64);
                if (ov > bv || (ov == bv && oi < bi)) { bv = ov; bi = oi; }
            }
            const float ow = (actc && lane == bi) ? ow_base : 0.0f;
            const float nu = fminf(1.0f, (ow + indv) + 0.98f * usg);

            if (actc) {
                sh_ow[lane] = ow;
                sh_indv[lane] = indv;
                sh_usage[lane] = nu;
            }
            if (own) {
                const int base = tb * M + lane;
                out[65536 + base]   = nu;                                   // usage_seq
                out[1376256 + base] = indv * (1.0f - 1e-8f) + 1e-8f;        // coref
                out[2686976 + base] = ow * (1.0f - 1e-8f) + 1e-8f;          // overwrite
            }
            if (jhalf == 0 && lane == 0) out[tb] = entp * (1.0f - 1e-8f) + 1e-8f; // ent
        }
        __syncthreads();   // (3)

        // ---- Phase D: memory update (g1 threads hold hwureg; own 10 rows) ----
        if (act && g == 1) {
            const float hc = hrow[c];
#pragma unroll
            for (int jj = 0; jj < M2; ++jj) {
                const float owj = sh_ow[jb2 + jj];
                const float inj = sh_indv[jb2 + jj];
                const float cd  = tanhf(sh_cand[jj][c] + hwureg);
                const float mo  = sh_mem[jj][c];
                sh_mem[jj][c] = owj * hc + (1.0f - owj - inj) * mo + inj * cd;
            }
        }
        __syncthreads();   // (4)
    }
}

extern "C" void kernel_launch(void* const* d_in, const int* in_sizes, int n_in,
                              void* d_out, int out_size, void* d_ws, size_t ws_size,
                              hipStream_t stream) {
    (void)in_sizes; (void)n_in; (void)ws_size; (void)out_size;
    const float* hs  = (const float*)d_in[0];
    const float* msk = (const float*)d_in[1];
    const float* We1 = (const float*)d_in[2];
    const float* be1 = (const float*)d_in[3];
    const float* We2 = (const float*)d_in[4];
    const float* be2 = (const float*)d_in[5];
    const float* Ws1 = (const float*)d_in[6];
    const float* bs1 = (const float*)d_in[7];
    const float* Ws2 = (const float*)d_in[8];
    const float* bs2 = (const float*)d_in[9];
    const float* Wu  = (const float*)d_in[10];
    const float* bu  = (const float*)d_in[11];
    float* out = (float*)d_out;

    // zero the sync flags/vals (stream-ordered, graph-capturable)
    hipMemsetAsync(d_ws, 0, 64 * 1024, stream);
    hipLaunchKernelGGL(wm_kernel, dim3(256), dim3(640), 0, stream,
                       hs, msk, We1, be1, We2, be2, Ws1, bs1, Ws2, bs2, Wu, bu,
                       out, (float*)d_ws);
}